// Round 1
// baseline (385.341 us; speedup 1.0000x reference)
//
#include <hip/hip_runtime.h>
#include <math.h>

#define NUM_TOKENS 16384
#define HD 4096
#define HD4 (HD / 4)          // 1024 float4 per row
#define NE 8
#define TOPK 2

#define BLOCK_THREADS 1024
#define WAVES_PER_BLOCK 16
#define TOK_PER_WAVE 4
#define TOK_PER_BLOCK (WAVES_PER_BLOCK * TOK_PER_WAVE)   // 64
#define NUM_BLOCKS (NUM_TOKENS / TOK_PER_BLOCK)          // 256

// Main kernel: one block per CU (128 KB LDS for gate), each wave computes 4 tokens.
__global__ __launch_bounds__(BLOCK_THREADS, 1)
void router_kernel(const float* __restrict__ hidden,
                   const float* __restrict__ gate,
                   float* __restrict__ out_w,    // [T,2]
                   float* __restrict__ out_idx,  // [T,2] stored as float
                   float* __restrict__ accum)    // [16]: counts[8], probsum[8]
{
    __shared__ float4 g_lds[NE * HD4];   // 8 * 1024 * 16B = 128 KB
    __shared__ float  s_acc[16];

    const int tid = threadIdx.x;

    // Stage gate weight into LDS (coalesced float4 copy).
    const float4* g4 = (const float4*)gate;
    #pragma unroll
    for (int i = 0; i < (NE * HD4) / BLOCK_THREADS; ++i)
        g_lds[tid + i * BLOCK_THREADS] = g4[tid + i * BLOCK_THREADS];
    if (tid < 16) s_acc[tid] = 0.0f;
    __syncthreads();

    const int wave = tid >> 6;
    const int lane = tid & 63;
    const int tokBase = (blockIdx.x * WAVES_PER_BLOCK + wave) * TOK_PER_WAVE;

    float acc[TOK_PER_WAVE][NE];
    #pragma unroll
    for (int t = 0; t < TOK_PER_WAVE; ++t)
        #pragma unroll
        for (int e = 0; e < NE; ++e) acc[t][e] = 0.0f;

    const float4* h4 = (const float4*)hidden;

    // K loop: lane handles float4 columns lane + 64k. Gate read once per 4 tokens.
    #pragma unroll 4
    for (int k = 0; k < HD4 / 64; ++k) {
        const int d4 = lane + k * 64;
        float4 g[NE];
        #pragma unroll
        for (int e = 0; e < NE; ++e) g[e] = g_lds[e * HD4 + d4];
        #pragma unroll
        for (int t = 0; t < TOK_PER_WAVE; ++t) {
            const float4 h = h4[(size_t)(tokBase + t) * HD4 + d4];
            #pragma unroll
            for (int e = 0; e < NE; ++e)
                acc[t][e] += h.x * g[e].x + h.y * g[e].y + h.z * g[e].z + h.w * g[e].w;
        }
    }

    // Butterfly reduce all 32 partials across the 64-lane wave.
    #pragma unroll
    for (int t = 0; t < TOK_PER_WAVE; ++t)
        #pragma unroll
        for (int e = 0; e < NE; ++e) {
            float v = acc[t][e];
            #pragma unroll
            for (int off = 32; off >= 1; off >>= 1)
                v += __shfl_xor(v, off, 64);
            acc[t][e] = v;
        }

    // Lanes 0..3: epilogue for token tokBase+lane.
    if (lane < TOK_PER_WAVE) {
        const int tok = tokBase + lane;
        float p[NE];
        float m = acc[lane][0];
        #pragma unroll
        for (int e = 1; e < NE; ++e) m = fmaxf(m, acc[lane][e]);
        float s = 0.0f;
        #pragma unroll
        for (int e = 0; e < NE; ++e) { p[e] = expf(acc[lane][e] - m); s += p[e]; }
        const float inv = 1.0f / s;
        #pragma unroll
        for (int e = 0; e < NE; ++e) p[e] *= inv;

        // top-2, ties -> lowest index (matches jax.lax.top_k)
        int i1 = 0;
        #pragma unroll
        for (int e = 1; e < NE; ++e) if (p[e] > p[i1]) i1 = e;
        int i2 = (i1 == 0) ? 1 : 0;
        #pragma unroll
        for (int e = 0; e < NE; ++e) if (e != i1 && p[e] > p[i2]) i2 = e;

        const float w1 = p[i1], w2 = p[i2];
        const float rs = 1.0f / (w1 + w2);
        out_w[tok * 2 + 0]   = w1 * rs;
        out_w[tok * 2 + 1]   = w2 * rs;
        out_idx[tok * 2 + 0] = (float)i1;
        out_idx[tok * 2 + 1] = (float)i2;

        atomicAdd(&s_acc[i1], 1.0f);
        atomicAdd(&s_acc[i2], 1.0f);
        #pragma unroll
        for (int e = 0; e < NE; ++e) atomicAdd(&s_acc[8 + e], p[e]);
    }
    __syncthreads();
    if (tid < 16) atomicAdd(&accum[tid], s_acc[tid]);
}

__global__ void finalize_kernel(const float* __restrict__ accum,
                                float* __restrict__ aux_out)
{
    if (threadIdx.x == 0) {
        const float invT = 1.0f / (float)NUM_TOKENS;
        float s = 0.0f;
        #pragma unroll
        for (int e = 0; e < NE; ++e)
            s += (accum[e] * invT) * (accum[8 + e] * invT);
        aux_out[0] = (float)NE * s;
    }
}

extern "C" void kernel_launch(void* const* d_in, const int* in_sizes, int n_in,
                              void* d_out, int out_size, void* d_ws, size_t ws_size,
                              hipStream_t stream) {
    const float* hidden = (const float*)d_in[0];   // [16384, 4096] f32
    const float* gate   = (const float*)d_in[1];   // [8, 4096] f32
    float* out = (float*)d_out;
    float* out_w   = out;                       // 16384*2
    float* out_idx = out + NUM_TOKENS * 2;      // 16384*2
    float* aux     = out + NUM_TOKENS * 4;      // 1
    float* accum   = (float*)d_ws;              // 16 floats

    hipMemsetAsync(accum, 0, 16 * sizeof(float), stream);
    router_kernel<<<NUM_BLOCKS, BLOCK_THREADS, 0, stream>>>(hidden, gate, out_w, out_idx, accum);
    finalize_kernel<<<1, 64, 0, stream>>>(accum, aux);
}

// Round 3
// 350.438 us; speedup vs baseline: 1.0996x; 1.0996x over previous
//
#include <hip/hip_runtime.h>
#include <math.h>

#define NUM_TOKENS 16384
#define HD 4096
#define HD4 (HD / 4)          // 1024 float4 per row
#define NE 8
#define TOPK 2

#define BLOCK_THREADS 1024
#define WAVES_PER_BLOCK 16
#define TOK_PER_WAVE 4
#define TOK_PER_BLOCK (WAVES_PER_BLOCK * TOK_PER_WAVE)   // 64
#define NUM_BLOCKS (NUM_TOKENS / TOK_PER_BLOCK)          // 256
#define KITERS (HD4 / 64)                                 // 16

// clang-native vector type: __builtin_nontemporal_load requires a true
// vector type, not HIP's struct-based float4.
typedef float vfloat4 __attribute__((ext_vector_type(4)));

// One block per CU (128 KB LDS gate stage). Each wave computes 4 tokens.
// Register-pressure-safe: K-loop unroll 1 + explicit 1-deep h prefetch.
__global__ __launch_bounds__(BLOCK_THREADS, 1)
void router_kernel(const float* __restrict__ hidden,
                   const float* __restrict__ gate,
                   float* __restrict__ out_w,    // [T,2]
                   float* __restrict__ out_idx,  // [T,2] stored as float
                   float* __restrict__ accum)    // [16]: counts[8], probsum[8]
{
    __shared__ vfloat4 g_lds[NE * HD4];   // 128 KB
    __shared__ float   s_acc[16];

    const int tid = threadIdx.x;

    // Stage gate weight into LDS (coalesced float4 copy).
    const vfloat4* g4 = (const vfloat4*)gate;
    #pragma unroll
    for (int i = 0; i < (NE * HD4) / BLOCK_THREADS; ++i)
        g_lds[tid + i * BLOCK_THREADS] = g4[tid + i * BLOCK_THREADS];
    if (tid < 16) s_acc[tid] = 0.0f;
    __syncthreads();

    const int wave = tid >> 6;
    const int lane = tid & 63;
    const int tokBase = (blockIdx.x * WAVES_PER_BLOCK + wave) * TOK_PER_WAVE;

    const vfloat4* h4 = (const vfloat4*)hidden;
    const size_t rowBase = (size_t)tokBase * HD4 + lane;

    float acc[TOK_PER_WAVE][NE];
    #pragma unroll
    for (int t = 0; t < TOK_PER_WAVE; ++t)
        #pragma unroll
        for (int e = 0; e < NE; ++e) acc[t][e] = 0.0f;

    // Prefetch k=0 hidden values.
    vfloat4 hbuf[TOK_PER_WAVE];
    #pragma unroll
    for (int t = 0; t < TOK_PER_WAVE; ++t)
        hbuf[t] = __builtin_nontemporal_load(&h4[rowBase + (size_t)t * HD4]);

    #pragma unroll 1
    for (int k = 0; k < KITERS; ++k) {
        vfloat4 hcur[TOK_PER_WAVE];
        #pragma unroll
        for (int t = 0; t < TOK_PER_WAVE; ++t) hcur[t] = hbuf[t];

        // Prefetch k+1 (1-deep register double buffer).
        if (k + 1 < KITERS) {
            const size_t off = rowBase + (size_t)(k + 1) * 64;
            #pragma unroll
            for (int t = 0; t < TOK_PER_WAVE; ++t)
                hbuf[t] = __builtin_nontemporal_load(&h4[off + (size_t)t * HD4]);
        }

        const int d4 = lane + k * 64;
        #pragma unroll
        for (int e = 0; e < NE; ++e) {
            const vfloat4 g = g_lds[e * HD4 + d4];   // one g live at a time
            #pragma unroll
            for (int t = 0; t < TOK_PER_WAVE; ++t)
                acc[t][e] += hcur[t].x * g.x + hcur[t].y * g.y
                           + hcur[t].z * g.z + hcur[t].w * g.w;
        }
    }

    // Butterfly reduce all 32 partials across the 64-lane wave.
    #pragma unroll
    for (int t = 0; t < TOK_PER_WAVE; ++t)
        #pragma unroll
        for (int e = 0; e < NE; ++e) {
            float v = acc[t][e];
            #pragma unroll
            for (int off = 32; off >= 1; off >>= 1)
                v += __shfl_xor(v, off, 64);
            acc[t][e] = v;
        }

    // Lanes 0..3: epilogue for token tokBase+lane.
    if (lane < TOK_PER_WAVE) {
        const int tok = tokBase + lane;
        float p[NE];
        float m = acc[lane][0];
        #pragma unroll
        for (int e = 1; e < NE; ++e) m = fmaxf(m, acc[lane][e]);
        float s = 0.0f;
        #pragma unroll
        for (int e = 0; e < NE; ++e) { p[e] = expf(acc[lane][e] - m); s += p[e]; }
        const float inv = 1.0f / s;
        #pragma unroll
        for (int e = 0; e < NE; ++e) p[e] *= inv;

        // top-2, ties -> lowest index (matches jax.lax.top_k)
        int i1 = 0;
        #pragma unroll
        for (int e = 1; e < NE; ++e) if (p[e] > p[i1]) i1 = e;
        int i2 = (i1 == 0) ? 1 : 0;
        #pragma unroll
        for (int e = 0; e < NE; ++e) if (e != i1 && p[e] > p[i2]) i2 = e;

        const float w1 = p[i1], w2 = p[i2];
        const float rs = 1.0f / (w1 + w2);
        out_w[tok * 2 + 0]   = w1 * rs;
        out_w[tok * 2 + 1]   = w2 * rs;
        out_idx[tok * 2 + 0] = (float)i1;
        out_idx[tok * 2 + 1] = (float)i2;

        atomicAdd(&s_acc[i1], 1.0f);
        atomicAdd(&s_acc[i2], 1.0f);
        #pragma unroll
        for (int e = 0; e < NE; ++e) atomicAdd(&s_acc[8 + e], p[e]);
    }
    __syncthreads();
    if (tid < 16) atomicAdd(&accum[tid], s_acc[tid]);
}

__global__ void finalize_kernel(const float* __restrict__ accum,
                                float* __restrict__ aux_out)
{
    if (threadIdx.x == 0) {
        const float invT = 1.0f / (float)NUM_TOKENS;
        float s = 0.0f;
        #pragma unroll
        for (int e = 0; e < NE; ++e)
            s += (accum[e] * invT) * (accum[8 + e] * invT);
        aux_out[0] = (float)NE * s;
    }
}

extern "C" void kernel_launch(void* const* d_in, const int* in_sizes, int n_in,
                              void* d_out, int out_size, void* d_ws, size_t ws_size,
                              hipStream_t stream) {
    const float* hidden = (const float*)d_in[0];   // [16384, 4096] f32
    const float* gate   = (const float*)d_in[1];   // [8, 4096] f32
    float* out = (float*)d_out;
    float* out_w   = out;                       // 16384*2
    float* out_idx = out + NUM_TOKENS * 2;      // 16384*2
    float* aux     = out + NUM_TOKENS * 4;      // 1
    float* accum   = (float*)d_ws;              // 16 floats

    (void)hipMemsetAsync(accum, 0, 16 * sizeof(float), stream);
    router_kernel<<<NUM_BLOCKS, BLOCK_THREADS, 0, stream>>>(hidden, gate, out_w, out_idx, accum);
    finalize_kernel<<<1, 64, 0, stream>>>(accum, aux);
}